// Round 7
// baseline (61.073 us; speedup 1.0000x reference)
//
#include <hip/hip_runtime.h>
#include <math.h>

// SH lmax=3 with normalization. f32 (N,3) -> f32 (N,16).
// One thread per output float4: no LDS, no barriers, fully coalesced stores.
// R7: nontemporal on BOTH streams (input streamed once; output written once).

typedef float f32x4 __attribute__((ext_vector_type(4)));

__global__ __launch_bounds__(256) void sh_lmax3_kernel(
    const float* __restrict__ ev, float* __restrict__ out, int n) {

    const float sqrt3  = 1.7320508075688772f;
    const float sqrt5  = 2.2360679774997896f;
    const float sqrt15 = 3.8729833462074170f;
    const float c30    = 1.0801234497346435f;  // sqrt(42)/6
    const float c31    = 2.6457513110645907f;  // sqrt(7)
    const float c32    = 1.6201851746019651f;  // sqrt(168)/8
    const float c33    = 1.3228756555322954f;  // 0.5*sqrt(7)

    int f = blockIdx.x * blockDim.x + threadIdx.x;  // output float4 index
    if (f >= n * 4) return;

    int e    = f >> 2;   // edge index
    int quad = f & 3;    // which float4 of the 16-float row

    float x = __builtin_nontemporal_load(&ev[3 * e + 0]);
    float y = __builtin_nontemporal_load(&ev[3 * e + 1]);
    float z = __builtin_nontemporal_load(&ev[3 * e + 2]);

    float s  = x * x + y * y + z * z;
    float rn = 1.0f / fmaxf(sqrtf(s), 1e-12f);
    x *= rn; y *= rn; z *= rn;

    float y2   = y * y;
    float x2z2 = x * x + z * z;

    float sh10 = sqrt3 * x;
    float sh11 = sqrt3 * y;
    float sh12 = sqrt3 * z;

    float sh20 = sqrt15 * x * z;
    float sh21 = sqrt15 * x * y;
    float sh22 = sqrt5 * (y2 - 0.5f * x2z2);
    float sh23 = sqrt15 * y * z;
    float sh24 = 0.5f * sqrt15 * (z * z - x * x);

    float sh30 = c30 * (sh20 * z + sh24 * x);
    float sh31 = c31 * sh20 * y;
    float sh32 = c32 * (4.0f * y2 - x2z2) * x;
    float sh33 = c33 * y * (2.0f * y2 - 3.0f * x2z2);
    float sh34 = c32 * z * (4.0f * y2 - x2z2);
    float sh35 = c31 * sh24 * y;
    float sh36 = c30 * (sh24 * z - sh20 * x);

    // Select this thread's quad via cndmask chains (no divergent stores).
    f32x4 v;
    v.x = quad == 0 ? 1.0f : quad == 1 ? sh20 : quad == 2 ? sh24 : sh33;
    v.y = quad == 0 ? sh10 : quad == 1 ? sh21 : quad == 2 ? sh30 : sh34;
    v.z = quad == 0 ? sh11 : quad == 1 ? sh22 : quad == 2 ? sh31 : sh35;
    v.w = quad == 0 ? sh12 : quad == 1 ? sh23 : quad == 2 ? sh32 : sh36;

    __builtin_nontemporal_store(v, &reinterpret_cast<f32x4*>(out)[f]);
}

extern "C" void kernel_launch(void* const* d_in, const int* in_sizes, int n_in,
                              void* d_out, int out_size, void* d_ws, size_t ws_size,
                              hipStream_t stream) {
    const float* ev = (const float*)d_in[0];
    float* out = (float*)d_out;
    int n = in_sizes[0] / 3;

    long long nf4 = (long long)n * 4;               // 12.8M output float4s
    int grid = (int)((nf4 + 255) / 256);            // 50000 blocks
    sh_lmax3_kernel<<<grid, 256, 0, stream>>>(ev, out, n);
}

// Round 8
// 38.237 us; speedup vs baseline: 1.5972x; 1.5972x over previous
//
#include <hip/hip_runtime.h>
#include <math.h>

// SH lmax=3 with normalization. f32 (N,3) -> f32 (N,16).
// One thread per output float4: no LDS, no barriers, fully coalesced stores.
// R8 = revert to R6 winner: nontemporal STORES only (write-once stream past L2),
// NORMAL loads (4-lane redundant reads must merge in L1/L2 — nt loads broke
// that and cost +60%, R7).

typedef float f32x4 __attribute__((ext_vector_type(4)));

__global__ __launch_bounds__(256) void sh_lmax3_kernel(
    const float* __restrict__ ev, float* __restrict__ out, int n) {

    const float sqrt3  = 1.7320508075688772f;
    const float sqrt5  = 2.2360679774997896f;
    const float sqrt15 = 3.8729833462074170f;
    const float c30    = 1.0801234497346435f;  // sqrt(42)/6
    const float c31    = 2.6457513110645907f;  // sqrt(7)
    const float c32    = 1.6201851746019651f;  // sqrt(168)/8
    const float c33    = 1.3228756555322954f;  // 0.5*sqrt(7)

    int f = blockIdx.x * blockDim.x + threadIdx.x;  // output float4 index
    if (f >= n * 4) return;

    int e    = f >> 2;   // edge index
    int quad = f & 3;    // which float4 of the 16-float row

    float x = ev[3 * e + 0];
    float y = ev[3 * e + 1];
    float z = ev[3 * e + 2];

    float s  = x * x + y * y + z * z;
    float rn = 1.0f / fmaxf(sqrtf(s), 1e-12f);
    x *= rn; y *= rn; z *= rn;

    float y2   = y * y;
    float x2z2 = x * x + z * z;

    float sh10 = sqrt3 * x;
    float sh11 = sqrt3 * y;
    float sh12 = sqrt3 * z;

    float sh20 = sqrt15 * x * z;
    float sh21 = sqrt15 * x * y;
    float sh22 = sqrt5 * (y2 - 0.5f * x2z2);
    float sh23 = sqrt15 * y * z;
    float sh24 = 0.5f * sqrt15 * (z * z - x * x);

    float sh30 = c30 * (sh20 * z + sh24 * x);
    float sh31 = c31 * sh20 * y;
    float sh32 = c32 * (4.0f * y2 - x2z2) * x;
    float sh33 = c33 * y * (2.0f * y2 - 3.0f * x2z2);
    float sh34 = c32 * z * (4.0f * y2 - x2z2);
    float sh35 = c31 * sh24 * y;
    float sh36 = c30 * (sh24 * z - sh20 * x);

    // Select this thread's quad via cndmask chains (no divergent stores).
    f32x4 v;
    v.x = quad == 0 ? 1.0f : quad == 1 ? sh20 : quad == 2 ? sh24 : sh33;
    v.y = quad == 0 ? sh10 : quad == 1 ? sh21 : quad == 2 ? sh30 : sh34;
    v.z = quad == 0 ? sh11 : quad == 1 ? sh22 : quad == 2 ? sh31 : sh35;
    v.w = quad == 0 ? sh12 : quad == 1 ? sh23 : quad == 2 ? sh32 : sh36;

    __builtin_nontemporal_store(v, &reinterpret_cast<f32x4*>(out)[f]);
}

extern "C" void kernel_launch(void* const* d_in, const int* in_sizes, int n_in,
                              void* d_out, int out_size, void* d_ws, size_t ws_size,
                              hipStream_t stream) {
    const float* ev = (const float*)d_in[0];
    float* out = (float*)d_out;
    int n = in_sizes[0] / 3;

    long long nf4 = (long long)n * 4;               // 12.8M output float4s
    int grid = (int)((nf4 + 255) / 256);            // 50000 blocks
    sh_lmax3_kernel<<<grid, 256, 0, stream>>>(ev, out, n);
}